// Round 2
// baseline (983.228 us; speedup 1.0000x reference)
//
#include <hip/hip_runtime.h>
#include <hip/hip_bf16.h>

typedef unsigned long long ull;

constexpr int NN = 4096;   // nodes
constexpr int HH = 4;      // heads
constexpr int DD = 128;    // per-head dim (DH == DO)
constexpr int NW = NN / 64; // 64-bit mask words per row

// ---------------------------------------------------------------------------
// Pack adj (int32 0/1) into transposed bitmask: mbT[w][i] holds bits for
// j = w*64 .. w*64+63 of row i.  2 MB total -> L2 resident for all later passes.
// ---------------------------------------------------------------------------
__global__ __launch_bounds__(256) void pack_mask_kernel(const int* __restrict__ adj,
                                                        ull* __restrict__ mbT) {
  const int i    = blockIdx.x;
  const int lane = threadIdx.x & 63;
  const int wave = threadIdx.x >> 6;
  for (int w = wave; w < NW; w += 4) {
    int v = adj[(size_t)i * NN + w * 64 + lane];
    ull m = __ballot(v > 0);
    if (lane == 0) mbT[(size_t)w * NN + i] = m;
  }
}

// ---------------------------------------------------------------------------
// Wh[h] = A_h @ W_h.   A_h = A + h*hsA, row stride sA, [NN x K];
// W_h = W + h*K*128, [K x 128];  out: Wh + h*NN*128.
// Block = 256 threads, 32 rows; K tiled by 64.  LDS 40KB.
// ---------------------------------------------------------------------------
__global__ __launch_bounds__(256) void gemm_kernel(const float* __restrict__ A,
                                                   int sA, long hsA,
                                                   const float* __restrict__ W,
                                                   float* __restrict__ Wh, int K) {
  __shared__ float Wt[64 * 128];  // 32KB: W rows k0..k0+63
  __shared__ float At[32 * 64];   // 8KB : A rows i0..i0+31, cols k0..k0+63
  const int t  = threadIdx.x;
  const int h  = blockIdx.y;
  const int i0 = blockIdx.x * 32;
  const int cg = t & 63;  // cols 2*cg, 2*cg+1
  const int rg = t >> 6;  // rows rg*8 .. rg*8+7
  const float* Ah = A + (long)h * hsA;
  const float* Wk = W + (long)h * K * 128;

  float2 acc[8];
#pragma unroll
  for (int r = 0; r < 8; ++r) acc[r] = make_float2(0.f, 0.f);

  for (int k0 = 0; k0 < K; k0 += 64) {
    const float4* Wsrc = (const float4*)(Wk + k0 * 128);  // contiguous 8192 floats
#pragma unroll
    for (int q = 0; q < 8; ++q) ((float4*)Wt)[t + 256 * q] = Wsrc[t + 256 * q];
#pragma unroll
    for (int q = 0; q < 2; ++q) {
      int idx = t + 256 * q;           // 512 float4 = 32x64 floats
      int r = idx >> 4, kq = (idx & 15) * 4;
      ((float4*)At)[idx] = *(const float4*)(Ah + (long)(i0 + r) * sA + k0 + kq);
    }
    __syncthreads();
#pragma unroll 8
    for (int kk = 0; kk < 64; kk += 2) {
      float2 w0 = *(const float2*)(Wt + kk * 128 + cg * 2);
      float2 w1 = *(const float2*)(Wt + (kk + 1) * 128 + cg * 2);
#pragma unroll
      for (int r = 0; r < 8; ++r) {
        float2 a = *(const float2*)(At + (rg * 8 + r) * 64 + kk);
        acc[r].x += a.x * w0.x + a.y * w1.x;
        acc[r].y += a.x * w0.y + a.y * w1.y;
      }
    }
    __syncthreads();
  }
#pragma unroll
  for (int r = 0; r < 8; ++r) {
    int row = i0 + rg * 8 + r;
    *(float2*)(Wh + ((long)h * NN + row) * 128 + cg * 2) = acc[r];
  }
}

// ---------------------------------------------------------------------------
// src[g] = Wh[g,:] . a_h[:128],  dst[g] = Wh[g,:] . a_h[128:], g = h*NN + i.
// One wave per row.
// ---------------------------------------------------------------------------
__global__ __launch_bounds__(256) void srcdst_kernel(const float* __restrict__ Wh,
                                                     const float* __restrict__ a,
                                                     float* __restrict__ src,
                                                     float* __restrict__ dst) {
  const int g    = blockIdx.x * 4 + (threadIdx.x >> 6);
  const int lane = threadIdx.x & 63;
  const int h    = g >> 12;
  const float* ah = a + h * 2 * DD;
  float2 w  = *(const float2*)(Wh + (size_t)g * DD + lane * 2);
  float2 as = *(const float2*)(ah + lane * 2);
  float2 ad = *(const float2*)(ah + DD + lane * 2);
  float s = w.x * as.x + w.y * as.y;
  float d = w.x * ad.x + w.y * ad.y;
#pragma unroll
  for (int off = 32; off > 0; off >>= 1) {
    s += __shfl_xor(s, off, 64);
    d += __shfl_xor(d, off, 64);
  }
  if (lane == 0) { src[g] = s; dst[g] = d; }
}

// ---------------------------------------------------------------------------
// Per row g = h*NN + i: m = max_j e_ij, r = 1/sum_j exp(e_ij - m),
// e_ij = mask ? lrelu(src_i + dst_j) : -9e15.  One wave per row, online.
// All-masked row degrades gracefully to uniform softmax (matches reference).
// ---------------------------------------------------------------------------
__global__ __launch_bounds__(256) void stats_kernel(const float* __restrict__ src,
                                                    const float* __restrict__ dst,
                                                    const ull* __restrict__ mbT,
                                                    float* __restrict__ mOut,
                                                    float* __restrict__ rOut) {
  const int g    = blockIdx.x * 4 + (threadIdx.x >> 6);
  const int lane = threadIdx.x & 63;
  const int h    = g >> 12;
  const int i    = g & (NN - 1);
  const float* dh = dst + (h << 12);
  const float si  = src[g];
  float m = -3.0e38f, l = 0.f;
  for (int w = 0; w < NW; ++w) {
    ull bits = mbT[(size_t)w * NN + i];
    float e = si + dh[w * 64 + lane];
    e = e > 0.f ? e : 0.2f * e;
    e = ((bits >> lane) & 1ull) ? e : -9e15f;
    float mn = fmaxf(m, e);
    l = l * __expf(m - mn) + __expf(e - mn);
    m = mn;
  }
  float ml = m;
#pragma unroll
  for (int off = 32; off > 0; off >>= 1) m = fmaxf(m, __shfl_xor(m, off, 64));
  float la = l * __expf(ml - m);
#pragma unroll
  for (int off = 32; off > 0; off >>= 1) la += __shfl_xor(la, off, 64);
  if (lane == 0) { mOut[g] = m; rOut[g] = 1.0f / la; }
}

// ---------------------------------------------------------------------------
// out[i0+ri, h*128 + c] = elu( sum_j p_ij * Wh[h][j][c] ),
// p_ij = exp(e_ij - m_i) * r_i computed on the fly (never materialize NxN).
// Block = 256 threads, TI=64 rows per block, j tiled by 64.
// LDS: Wh tile 32KB + padded p tile 17KB.
// ---------------------------------------------------------------------------
constexpr int PSTR = 68;  // p row stride (floats), padded: breaks 8-way conflicts

#define FMA4(A, F, Wv) { (A).x += (F) * (Wv).x; (A).y += (F) * (Wv).y; \
                         (A).z += (F) * (Wv).z; (A).w += (F) * (Wv).w; }
#define ELU4(V) { (V).x = (V).x > 0.f ? (V).x : __expf((V).x) - 1.f; \
                  (V).y = (V).y > 0.f ? (V).y : __expf((V).y) - 1.f; \
                  (V).z = (V).z > 0.f ? (V).z : __expf((V).z) - 1.f; \
                  (V).w = (V).w > 0.f ? (V).w : __expf((V).w) - 1.f; }

__global__ __launch_bounds__(256) void att_accum_kernel(
    const float* __restrict__ Wh, const float* __restrict__ src,
    const float* __restrict__ dst, const float* __restrict__ mIn,
    const float* __restrict__ rIn, const ull* __restrict__ mbT,
    float* __restrict__ out, int outStride) {
  __shared__ float whl[64 * 128];   // 32KB
  __shared__ float pl[64 * PSTR];   // 17KB
  const int t  = threadIdx.x;
  const int h  = blockIdx.y;
  const int i0 = blockIdx.x * 64;

  // p-compute assignment: thread -> (row pi, 16 j's starting at jb)
  const int pi = t & 63;
  const int jb = (t >> 6) * 16;
  const int gp = (h << 12) + i0 + pi;
  const float s_i = src[gp];
  const float m_i = mIn[gp];
  const float r_i = rIn[gp];
  const float* dh  = dst + (h << 12);
  const float* WhH = Wh + ((size_t)h << 12) * DD;

  // accumulate assignment: thread -> 4 rows (rg*4..+3) x 8 cols (cg*8..+7)
  const int cg = t & 15;
  const int rg = t >> 4;
  float4 acc[4][2];
#pragma unroll
  for (int r = 0; r < 4; ++r) {
    acc[r][0] = make_float4(0.f, 0.f, 0.f, 0.f);
    acc[r][1] = make_float4(0.f, 0.f, 0.f, 0.f);
  }

  for (int w = 0; w < NW; ++w) {
    // stage Wh rows w*64 .. w*64+63 (coalesced float4)
    const float4* wsrc = (const float4*)(WhH + (size_t)w * 64 * DD);
#pragma unroll
    for (int q = 0; q < 8; ++q) ((float4*)whl)[t + 256 * q] = wsrc[t + 256 * q];
    // compute 16 p values for row pi
    ull bits = mbT[(size_t)w * NN + i0 + pi] >> jb;
    const float* dj = dh + w * 64 + jb;
#pragma unroll
    for (int q = 0; q < 16; ++q) {
      float e = s_i + dj[q];
      e = e > 0.f ? e : 0.2f * e;
      e = ((bits >> q) & 1ull) ? e : -9e15f;
      pl[pi * PSTR + jb + q] = __expf(e - m_i) * r_i;
    }
    __syncthreads();
#pragma unroll 4
    for (int jj = 0; jj < 64; jj += 4) {
      float4 pv[4];
#pragma unroll
      for (int r = 0; r < 4; ++r)
        pv[r] = *(const float4*)(pl + (rg * 4 + r) * PSTR + jj);
#pragma unroll
      for (int u = 0; u < 4; ++u) {
        float4 w0 = *(const float4*)(whl + (jj + u) * DD + cg * 8);
        float4 w1 = *(const float4*)(whl + (jj + u) * DD + cg * 8 + 4);
#pragma unroll
        for (int r = 0; r < 4; ++r) {
          float f = ((const float*)&pv[r])[u];  // u is compile-time after unroll
          FMA4(acc[r][0], f, w0);
          FMA4(acc[r][1], f, w1);
        }
      }
    }
    __syncthreads();
  }
#pragma unroll
  for (int r = 0; r < 4; ++r) {
    int row = i0 + rg * 4 + r;
    float4 v0 = acc[r][0], v1 = acc[r][1];
    ELU4(v0);
    ELU4(v1);
    float* op = out + (size_t)row * outStride + h * DD + cg * 8;
    *(float4*)op = v0;
    *(float4*)(op + 4) = v1;
  }
}

// ---------------------------------------------------------------------------
extern "C" void kernel_launch(void* const* d_in, const int* in_sizes, int n_in,
                              void* d_out, int out_size, void* d_ws, size_t ws_size,
                              hipStream_t stream) {
  const float* chems = (const float*)d_in[0];  // [H, N, 128]
  const int*   adj   = (const int*)d_in[1];    // [N, N]
  const float* W1    = (const float*)d_in[2];  // [H, 128, 128]
  const float* a1    = (const float*)d_in[3];  // [H, 256]
  const float* W2    = (const float*)d_in[4];  // [H, 512, 128]
  const float* a2    = (const float*)d_in[5];  // [H, 256]
  float* out = (float*)d_out;                  // [N, 512]

  char* p = (char*)d_ws;
  auto alloc = [&](size_t bytes) { char* r = p; p += bytes; return r; };
  ull*   mbT  = (ull*)alloc((size_t)NW * NN * 8);            // 2 MB
  float* Wh1  = (float*)alloc((size_t)HH * NN * DD * 4);     // 8 MB
  float* Wh2  = (float*)alloc((size_t)HH * NN * DD * 4);     // 8 MB
  float* x    = (float*)alloc((size_t)NN * HH * DD * 4);     // 8 MB
  float* src1 = (float*)alloc((size_t)HH * NN * 4);
  float* dst1 = (float*)alloc((size_t)HH * NN * 4);
  float* m1   = (float*)alloc((size_t)HH * NN * 4);
  float* r1   = (float*)alloc((size_t)HH * NN * 4);
  float* src2 = (float*)alloc((size_t)HH * NN * 4);
  float* dst2 = (float*)alloc((size_t)HH * NN * 4);
  float* m2   = (float*)alloc((size_t)HH * NN * 4);
  float* r2   = (float*)alloc((size_t)HH * NN * 4);
  (void)ws_size; (void)in_sizes; (void)n_in; (void)out_size;

  pack_mask_kernel<<<NN, 256, 0, stream>>>(adj, mbT);

  // ---- stage 1 ----
  gemm_kernel<<<dim3(NN / 32, HH), 256, 0, stream>>>(chems, DD, (long)NN * DD, W1, Wh1, DD);
  srcdst_kernel<<<(HH * NN) / 4, 256, 0, stream>>>(Wh1, a1, src1, dst1);
  stats_kernel<<<(HH * NN) / 4, 256, 0, stream>>>(src1, dst1, mbT, m1, r1);
  att_accum_kernel<<<dim3(NN / 64, HH), 256, 0, stream>>>(Wh1, src1, dst1, m1, r1, mbT,
                                                          x, HH * DD);
  // ---- stage 2 ----
  gemm_kernel<<<dim3(NN / 32, HH), 256, 0, stream>>>(x, HH * DD, 0L, W2, Wh2, HH * DD);
  srcdst_kernel<<<(HH * NN) / 4, 256, 0, stream>>>(Wh2, a2, src2, dst2);
  stats_kernel<<<(HH * NN) / 4, 256, 0, stream>>>(src2, dst2, mbT, m2, r2);
  att_accum_kernel<<<dim3(NN / 64, HH), 256, 0, stream>>>(Wh2, src2, dst2, m2, r2, mbT,
                                                          out, HH * DD);
}

// Round 3
// 417.627 us; speedup vs baseline: 2.3543x; 2.3543x over previous
//
#include <hip/hip_runtime.h>
#include <hip/hip_bf16.h>

typedef unsigned long long ull;
typedef __attribute__((ext_vector_type(8))) short short8;
typedef __attribute__((ext_vector_type(8))) unsigned short us8;
typedef __attribute__((ext_vector_type(4))) float f32x4;

constexpr int NN = 4096;   // nodes
constexpr int HH = 4;      // heads
constexpr int DD = 128;    // per-head dim (DH == DO)
constexpr int NW = NN / 64; // 64-bit mask words per row

// float -> bf16 round-to-nearest-even (no NaN handling; inputs are finite)
__device__ inline unsigned short f2bf(float x) {
  unsigned u = __float_as_uint(x);
  u += 0x7FFFu + ((u >> 16) & 1u);
  return (unsigned short)(u >> 16);
}

// ---------------------------------------------------------------------------
// Pack adj (int32 0/1) into transposed bitmask: mbT[w][i] holds bits for
// j = w*64 .. w*64+63 of row i.  2 MB -> L2 resident for all later passes.
// ---------------------------------------------------------------------------
__global__ __launch_bounds__(256) void pack_mask_kernel(const int* __restrict__ adj,
                                                        ull* __restrict__ mbT) {
  const int i    = blockIdx.x;
  const int lane = threadIdx.x & 63;
  const int wave = threadIdx.x >> 6;
  for (int w = wave; w < NW; w += 4) {
    int v = adj[(size_t)i * NN + w * 64 + lane];
    ull m = __ballot(v > 0);
    if (lane == 0) mbT[(size_t)w * NN + i] = m;
  }
}

// ---------------------------------------------------------------------------
// Wh[h] = A_h @ W_h (fp32 out, for srcdst/stats)  +  WhT bf16 transposed copy
// [h][c][j] (for the MFMA attention pass).
// Block = 256 threads, 32 rows; K tiled by 64.  LDS 40KB.
// ---------------------------------------------------------------------------
__global__ __launch_bounds__(256) void gemm_kernel(const float* __restrict__ A,
                                                   int sA, long hsA,
                                                   const float* __restrict__ W,
                                                   float* __restrict__ Wh,
                                                   unsigned short* __restrict__ WhT,
                                                   int K) {
  __shared__ float Wt[64 * 128];  // 32KB: W rows k0..k0+63
  __shared__ float At[32 * 64];   // 8KB : A rows i0..i0+31, cols k0..k0+63
  const int t  = threadIdx.x;
  const int h  = blockIdx.y;
  const int i0 = blockIdx.x * 32;
  const int cg = t & 63;  // cols 2*cg, 2*cg+1
  const int rg = t >> 6;  // rows rg*8 .. rg*8+7
  const float* Ah = A + (long)h * hsA;
  const float* Wk = W + (long)h * K * 128;

  float2 acc[8];
#pragma unroll
  for (int r = 0; r < 8; ++r) acc[r] = make_float2(0.f, 0.f);

  for (int k0 = 0; k0 < K; k0 += 64) {
    const float4* Wsrc = (const float4*)(Wk + k0 * 128);  // contiguous 8192 floats
#pragma unroll
    for (int q = 0; q < 8; ++q) ((float4*)Wt)[t + 256 * q] = Wsrc[t + 256 * q];
#pragma unroll
    for (int q = 0; q < 2; ++q) {
      int idx = t + 256 * q;           // 512 float4 = 32x64 floats
      int r = idx >> 4, kq = (idx & 15) * 4;
      ((float4*)At)[idx] = *(const float4*)(Ah + (long)(i0 + r) * sA + k0 + kq);
    }
    __syncthreads();
#pragma unroll 8
    for (int kk = 0; kk < 64; kk += 2) {
      float2 w0 = *(const float2*)(Wt + kk * 128 + cg * 2);
      float2 w1 = *(const float2*)(Wt + (kk + 1) * 128 + cg * 2);
#pragma unroll
      for (int r = 0; r < 8; ++r) {
        float2 a = *(const float2*)(At + (rg * 8 + r) * 64 + kk);
        acc[r].x += a.x * w0.x + a.y * w1.x;
        acc[r].y += a.x * w0.y + a.y * w1.y;
      }
    }
    __syncthreads();
  }
#pragma unroll
  for (int r = 0; r < 8; ++r) {
    int row = i0 + rg * 8 + r;
    *(float2*)(Wh + ((long)h * NN + row) * 128 + cg * 2) = acc[r];
  }
  // bf16 transposed copy: WhT[h][c][j], 8 consecutive j per column = 16B store
  us8 v0, v1;
#pragma unroll
  for (int r = 0; r < 8; ++r) { v0[r] = f2bf(acc[r].x); v1[r] = f2bf(acc[r].y); }
  unsigned short* base = WhT + ((size_t)h * DD + cg * 2) * NN + i0 + rg * 8;
  *(us8*)(base) = v0;
  *(us8*)(base + NN) = v1;
}

// ---------------------------------------------------------------------------
// src[g] = Wh[g,:] . a_h[:128],  dst[g] = Wh[g,:] . a_h[128:], g = h*NN + i.
// ---------------------------------------------------------------------------
__global__ __launch_bounds__(256) void srcdst_kernel(const float* __restrict__ Wh,
                                                     const float* __restrict__ a,
                                                     float* __restrict__ src,
                                                     float* __restrict__ dst) {
  const int g    = blockIdx.x * 4 + (threadIdx.x >> 6);
  const int lane = threadIdx.x & 63;
  const int h    = g >> 12;
  const float* ah = a + h * 2 * DD;
  float2 w  = *(const float2*)(Wh + (size_t)g * DD + lane * 2);
  float2 as = *(const float2*)(ah + lane * 2);
  float2 ad = *(const float2*)(ah + DD + lane * 2);
  float s = w.x * as.x + w.y * as.y;
  float d = w.x * ad.x + w.y * ad.y;
#pragma unroll
  for (int off = 32; off > 0; off >>= 1) {
    s += __shfl_xor(s, off, 64);
    d += __shfl_xor(d, off, 64);
  }
  if (lane == 0) { src[g] = s; dst[g] = d; }
}

// ---------------------------------------------------------------------------
// Per row g: m = max_j e_ij, r = 1/sum_j exp(e_ij - m),
// e_ij = mask ? lrelu(src_i + dst_j) : -9e15.  One wave per row, online.
// ---------------------------------------------------------------------------
__global__ __launch_bounds__(256) void stats_kernel(const float* __restrict__ src,
                                                    const float* __restrict__ dst,
                                                    const ull* __restrict__ mbT,
                                                    float* __restrict__ mOut,
                                                    float* __restrict__ rOut) {
  const int g    = blockIdx.x * 4 + (threadIdx.x >> 6);
  const int lane = threadIdx.x & 63;
  const int h    = g >> 12;
  const int i    = g & (NN - 1);
  const float* dh = dst + (h << 12);
  const float si  = src[g];
  float m = -3.0e38f, l = 0.f;
  for (int w = 0; w < NW; ++w) {
    ull bits = mbT[(size_t)w * NN + i];
    float e = si + dh[w * 64 + lane];
    e = e > 0.f ? e : 0.2f * e;
    e = ((bits >> lane) & 1ull) ? e : -9e15f;
    float mn = fmaxf(m, e);
    l = l * __expf(m - mn) + __expf(e - mn);
    m = mn;
  }
  float ml = m;
#pragma unroll
  for (int off = 32; off > 0; off >>= 1) m = fmaxf(m, __shfl_xor(m, off, 64));
  float la = l * __expf(ml - m);
#pragma unroll
  for (int off = 32; off > 0; off >>= 1) la += __shfl_xor(la, off, 64);
  if (lane == 0) { mOut[g] = m; rOut[g] = 1.0f / la; }
}

// ---------------------------------------------------------------------------
// MFMA attention accumulate: out[i0+ri, h*128+c] = elu( sum_j p_ij Wh[j][c] ).
// P generated on the fly in bf16; Wh consumed from bf16 transposed WhT.
// Tile: 32 rows x 128 cols, 4 waves (each 16r x 64c, 4 accum frags).
// LDS XOR-swizzle (chunk ^= row&7) keeps ds_read_b128/ds_write_b128 uniform
// across banks (write & read sides use the same involution — rule 21).
// ---------------------------------------------------------------------------
__global__ __launch_bounds__(256) void att_mfma_kernel(
    const unsigned short* __restrict__ WhT, const float* __restrict__ src,
    const float* __restrict__ dst, const float* __restrict__ mIn,
    const float* __restrict__ rIn, const ull* __restrict__ mbT,
    float* __restrict__ out, int outStride) {
  __shared__ unsigned short whl[128 * 64];  // [c][j-chunk swizzled]  16KB
  __shared__ unsigned short pl[32 * 64];    // [r][j-chunk swizzled]   4KB
  const int t    = threadIdx.x;
  const int h    = blockIdx.y;
  const int i0   = blockIdx.x * 32;
  const int lane = t & 63;
  const int wv   = t >> 6;
  const int l16  = lane >> 4;
  const int l15  = lane & 15;

  // p-gen assignment: row pi (0..31), j-chunk pg (8 j's)
  const int pi = t & 31;
  const int pg = t >> 5;
  const int gp = (h << 12) + i0 + pi;
  const float s_i = src[gp];
  const float m_i = mIn[gp];
  const float r_i = rIn[gp];
  const float* dh = dst + (h << 12);
  const unsigned short* WhTh = WhT + (size_t)h * DD * NN;

  // mfma assignment: wave (wr,wc) sub-tile 16 x 64
  const int wr = (wv >> 1) * 16;
  const int wc = (wv & 1) * 64;
  const int arow = wr + l15;

  f32x4 acc[4];
#pragma unroll
  for (int cf = 0; cf < 4; ++cf) acc[cf] = (f32x4){0.f, 0.f, 0.f, 0.f};

  for (int w = 0; w < NW; ++w) {
    const int j0 = w * 64;
    // stage Wh tile: 128 cols x 64 j (1024 16B-chunks, 4/thread, coalesced 128B)
#pragma unroll
    for (int q = 0; q < 4; ++q) {
      int idx = t + 256 * q;
      int c = idx >> 3, g = idx & 7;
      us8 v = *(const us8*)(WhTh + (size_t)c * NN + j0 + g * 8);
      *(us8*)(whl + c * 64 + ((g ^ (c & 7)) * 8)) = v;
    }
    // generate 8 bf16 p-values for row pi
    ull bits = mbT[(size_t)w * NN + i0 + pi] >> (pg * 8);
    f32x4 d0 = *(const f32x4*)(dh + j0 + pg * 8);
    f32x4 d1 = *(const f32x4*)(dh + j0 + pg * 8 + 4);
    us8 pv;
#pragma unroll
    for (int q = 0; q < 8; ++q) {
      float e = s_i + (q < 4 ? d0[q] : d1[q - 4]);
      e = e > 0.f ? e : 0.2f * e;
      e = ((bits >> q) & 1ull) ? e : -9e15f;
      pv[q] = f2bf(__expf(e - m_i) * r_i);
    }
    *(us8*)(pl + pi * 64 + ((pg ^ (pi & 7)) * 8)) = pv;
    __syncthreads();
    // 2 K=32 steps: A = P[16r x 32j], B = Wh[32j x 16c]
#pragma unroll
    for (int s = 0; s < 2; ++s) {
      int ag = s * 4 + l16;  // j-chunk this lane needs
      short8 a = *(const short8*)(pl + arow * 64 + ((ag ^ (arow & 7)) * 8));
#pragma unroll
      for (int cf = 0; cf < 4; ++cf) {
        int c = wc + cf * 16 + l15;
        short8 b = *(const short8*)(whl + c * 64 + ((ag ^ (c & 7)) * 8));
        acc[cf] = __builtin_amdgcn_mfma_f32_16x16x32_bf16(a, b, acc[cf], 0, 0, 0);
      }
    }
    __syncthreads();
  }
  // epilogue: D layout col=lane&15, row=(lane>>4)*4+reg  [m89]
#pragma unroll
  for (int cf = 0; cf < 4; ++cf) {
    int col = h * DD + wc + cf * 16 + l15;
#pragma unroll
    for (int r = 0; r < 4; ++r) {
      int row = i0 + wr + l16 * 4 + r;
      float v = acc[cf][r];
      v = v > 0.f ? v : __expf(v) - 1.f;
      out[(size_t)row * outStride + col] = v;
    }
  }
}

// ---------------------------------------------------------------------------
extern "C" void kernel_launch(void* const* d_in, const int* in_sizes, int n_in,
                              void* d_out, int out_size, void* d_ws, size_t ws_size,
                              hipStream_t stream) {
  const float* chems = (const float*)d_in[0];  // [H, N, 128]
  const int*   adj   = (const int*)d_in[1];    // [N, N]
  const float* W1    = (const float*)d_in[2];  // [H, 128, 128]
  const float* a1    = (const float*)d_in[3];  // [H, 256]
  const float* W2    = (const float*)d_in[4];  // [H, 512, 128]
  const float* a2    = (const float*)d_in[5];  // [H, 256]
  float* out = (float*)d_out;                  // [N, 512]

  char* p = (char*)d_ws;
  auto alloc = [&](size_t bytes) { char* r = p; p += bytes; return r; };
  ull*   mbT  = (ull*)alloc((size_t)NW * NN * 8);                 // 2 MB
  float* Wh1  = (float*)alloc((size_t)HH * NN * DD * 4);          // 8 MB
  float* Wh2  = (float*)alloc((size_t)HH * NN * DD * 4);          // 8 MB
  float* x    = (float*)alloc((size_t)NN * HH * DD * 4);          // 8 MB
  unsigned short* WhT1 = (unsigned short*)alloc((size_t)HH * DD * NN * 2);  // 4 MB
  unsigned short* WhT2 = (unsigned short*)alloc((size_t)HH * DD * NN * 2);  // 4 MB
  float* src1 = (float*)alloc((size_t)HH * NN * 4);
  float* dst1 = (float*)alloc((size_t)HH * NN * 4);
  float* m1   = (float*)alloc((size_t)HH * NN * 4);
  float* r1   = (float*)alloc((size_t)HH * NN * 4);
  float* src2 = (float*)alloc((size_t)HH * NN * 4);
  float* dst2 = (float*)alloc((size_t)HH * NN * 4);
  float* m2   = (float*)alloc((size_t)HH * NN * 4);
  float* r2   = (float*)alloc((size_t)HH * NN * 4);
  (void)ws_size; (void)in_sizes; (void)n_in; (void)out_size;

  pack_mask_kernel<<<NN, 256, 0, stream>>>(adj, mbT);

  // ---- stage 1 ----
  gemm_kernel<<<dim3(NN / 32, HH), 256, 0, stream>>>(chems, DD, (long)NN * DD, W1,
                                                     Wh1, WhT1, DD);
  srcdst_kernel<<<(HH * NN) / 4, 256, 0, stream>>>(Wh1, a1, src1, dst1);
  stats_kernel<<<(HH * NN) / 4, 256, 0, stream>>>(src1, dst1, mbT, m1, r1);
  att_mfma_kernel<<<dim3(NN / 32, HH), 256, 0, stream>>>(WhT1, src1, dst1, m1, r1,
                                                         mbT, x, HH * DD);
  // ---- stage 2 ----
  gemm_kernel<<<dim3(NN / 32, HH), 256, 0, stream>>>(x, HH * DD, 0L, W2,
                                                     Wh2, WhT2, HH * DD);
  srcdst_kernel<<<(HH * NN) / 4, 256, 0, stream>>>(Wh2, a2, src2, dst2);
  stats_kernel<<<(HH * NN) / 4, 256, 0, stream>>>(src2, dst2, mbT, m2, r2);
  att_mfma_kernel<<<dim3(NN / 32, HH), 256, 0, stream>>>(WhT2, src2, dst2, m2, r2,
                                                         mbT, out, HH * DD);
}